// Round 2
// baseline (607.683 us; speedup 1.0000x reference)
//
#include <hip/hip_runtime.h>
#include <hip/hip_bf16.h>

typedef unsigned short u16;
typedef unsigned int u32;

#define HD 256
#define VD 8192
#define SD 4096
#define H2 512

// ws float offsets (total 6144 floats = 24 KB)
#define WS_FLAG  0
#define WS_WAH   64
#define WS_STATS 320
#define WS_CI    384
#define WS_G     896
#define WS_HN    1664
#define WS_EIJ   2048   // ..6144

__device__ __forceinline__ float bflo(u32 w) { return __uint_as_float(w << 16); }
__device__ __forceinline__ float bfhi(u32 w) { return __uint_as_float(w & 0xffff0000u); }
__device__ __forceinline__ float bfu(u16 u)  { return __uint_as_float(((u32)u) << 16); }

// dtype-agnostic loads/stores: bf=1 -> bf16, bf=0 -> f32
__device__ __forceinline__ float ldf(const void* p, long i, int bf) {
    return bf ? bfu(((const u16*)p)[i]) : ((const float*)p)[i];
}
__device__ __forceinline__ float4 ldf4(const void* p, long i, int bf) {  // i % 4 == 0
    if (bf) {
        uint2 u = *(const uint2*)((const u16*)p + i);
        return make_float4(bflo(u.x), bfhi(u.x), bflo(u.y), bfhi(u.y));
    }
    return *(const float4*)((const float*)p + i);
}
__device__ __forceinline__ void stf(void* p, long i, int bf, float v) {
    if (bf) ((__hip_bfloat16*)p)[i] = __float2bfloat16(v);
    else    ((float*)p)[i] = v;
}
__device__ __forceinline__ float dot4(float4 a, float4 b, float acc) {
    acc = fmaf(a.x, b.x, acc); acc = fmaf(a.y, b.y, acc);
    acc = fmaf(a.z, b.z, acc); return fmaf(a.w, b.w, acc);
}

// KS: detect input dtype. Even u16 words of emb: bf16 data -> plausible small
// values; f32 data -> mantissa-garbage words. Writes flag (1=bf16, 0=f32).
__global__ __launch_bounds__(64) void ks_sniff(const void* emb, int* flag) {
    int t = threadIdx.x;
    const u16* p = (const u16*)emb;
    int ok = 0;
    #pragma unroll
    for (int j = 0; j < 2; ++j) {
        float x = fabsf(bfu(p[2 * (t + 64 * j)]));
        ok += (x == 0.f || (x > 3e-6f && x < 0.25f)) ? 1 : 0;
    }
    #pragma unroll
    for (int o = 32; o; o >>= 1) ok += __shfl_xor(ok, o);
    if (t == 0) flag[0] = (ok >= 96) ? 1 : 0;
}

// K0: wa_h = Wa_w @ hidden + Wa_b
__global__ __launch_bounds__(256) void k0_wah(const void* Wa_w, const void* Wa_b,
                                              const void* hidden, const int* flag,
                                              float* __restrict__ wa_h) {
    __shared__ __align__(16) float hs[HD];
    int t = threadIdx.x; int bf = flag[0];
    hs[t] = ldf(hidden, t, bf);
    __syncthreads();
    float acc = 0.f;
    for (int k = 0; k < HD; k += 4)
        acc = dot4(ldf4(Wa_w, (long)t * HD + k, bf), *(const float4*)&hs[k], acc);
    wa_h[t] = acc + ldf(Wa_b, t, bf);
}

// K1: Eij[s] = Va . tanh(wa_h + Ua_b + Ua_w @ enc[s]); 16 s-rows per block.
// Wave sg owns s-rows sg*4..sg*4+3; lane owns units 4*lane..4*lane+3.
__global__ __launch_bounds__(256) void k1_scores(const void* enc, const void* Ua_w,
                                                 const void* Ua_b, const void* Va_w,
                                                 const void* Va_b,
                                                 const float* __restrict__ wa_h,
                                                 const int* flag,
                                                 float* __restrict__ Eij) {
    __shared__ __align__(16) float encs[16 * H2];
    int t = threadIdx.x; int bf = flag[0];
    int lane = t & 63, sg = t >> 6;
    int h0 = lane * 4;
    long s0 = (long)blockIdx.x * 16;

    for (int i = t * 4; i < 16 * H2; i += 1024) {
        float4 v = ldf4(enc, s0 * H2 + i, bf);
        *(float4*)&encs[i] = v;
    }
    __syncthreads();

    float acc[4][4];
    #pragma unroll
    for (int a = 0; a < 4; ++a)
        #pragma unroll
        for (int b = 0; b < 4; ++b) acc[a][b] = 0.f;

    for (int kc = 0; kc < H2; kc += 4) {
        float4 a0 = ldf4(Ua_w, (long)(h0 + 0) * H2 + kc, bf);
        float4 a1 = ldf4(Ua_w, (long)(h0 + 1) * H2 + kc, bf);
        float4 a2 = ldf4(Ua_w, (long)(h0 + 2) * H2 + kc, bf);
        float4 a3 = ldf4(Ua_w, (long)(h0 + 3) * H2 + kc, bf);
        #pragma unroll
        for (int ss = 0; ss < 4; ++ss) {
            float4 ev = *(const float4*)&encs[(sg * 4 + ss) * H2 + kc];
            acc[ss][0] = dot4(a0, ev, acc[ss][0]);
            acc[ss][1] = dot4(a1, ev, acc[ss][1]);
            acc[ss][2] = dot4(a2, ev, acc[ss][2]);
            acc[ss][3] = dot4(a3, ev, acc[ss][3]);
        }
    }

    float bias[4], va[4];
    #pragma unroll
    for (int j = 0; j < 4; ++j) {
        bias[j] = wa_h[h0 + j] + ldf(Ua_b, h0 + j, bf);
        va[j]   = ldf(Va_w, h0 + j, bf);
    }
    float vb = ldf(Va_b, 0, bf);
    #pragma unroll
    for (int ss = 0; ss < 4; ++ss) {
        float v = 0.f;
        #pragma unroll
        for (int j = 0; j < 4; ++j)
            v += va[j] * tanhf(acc[ss][j] + bias[j]);
        #pragma unroll
        for (int o = 32; o; o >>= 1) v += __shfl_xor(v, o);
        if (lane == 0) Eij[s0 + sg * 4 + ss] = v + vb;
    }
}

// K2: softmax stats over Eij (f32 ws) + zero Ci
__global__ __launch_bounds__(256) void k2_stats(const float* __restrict__ Eij,
                                                float* __restrict__ stats,
                                                float* __restrict__ Ci) {
    __shared__ float sh[4];
    int t = threadIdx.x, lane = t & 63, wv = t >> 6;
    float m = -1e30f;
    for (int i = t; i < SD; i += 256) m = fmaxf(m, Eij[i]);
    #pragma unroll
    for (int o = 32; o; o >>= 1) m = fmaxf(m, __shfl_xor(m, o));
    if (lane == 0) sh[wv] = m;
    __syncthreads();
    m = fmaxf(fmaxf(sh[0], sh[1]), fmaxf(sh[2], sh[3]));
    __syncthreads();
    float s = 0.f;
    for (int i = t; i < SD; i += 256) s += __expf(Eij[i] - m);
    #pragma unroll
    for (int o = 32; o; o >>= 1) s += __shfl_xor(s, o);
    if (lane == 0) sh[wv] = s;
    __syncthreads();
    s = sh[0] + sh[1] + sh[2] + sh[3];
    if (t == 0) { stats[0] = m; stats[1] = 1.f / s; }
    for (int i = t; i < H2; i += 256) Ci[i] = 0.f;
}

// K3: aij -> out[8448..], Ci += sum aij*enc
__global__ __launch_bounds__(256) void k3_ci(const float* __restrict__ Eij,
                                             const float* __restrict__ stats,
                                             const void* enc, const int* flag,
                                             void* out, float* __restrict__ Ci) {
    __shared__ float a[64];
    int t = threadIdx.x; int bf = flag[0];
    long s0 = (long)blockIdx.x * 64;
    if (t < 64) {
        float v = __expf(Eij[s0 + t] - stats[0]) * stats[1];
        a[t] = v;
        stf(out, 8448 + s0 + t, bf, v);
    }
    __syncthreads();
    float acc0 = 0.f, acc1 = 0.f;
    for (int s = 0; s < 64; ++s) {
        float av = a[s];
        acc0 = fmaf(av, ldf(enc, (s0 + s) * H2 + t, bf), acc0);
        acc1 = fmaf(av, ldf(enc, (s0 + s) * H2 + t + 256, bf), acc1);
    }
    atomicAdd(Ci + t, acc0);
    atomicAdd(Ci + t + 256, acc1);
}

// K4: G[g*256+i] = U_g[i,:].y (+ W_g[i,:].hidden for z,r) + biases; 1 wave/row
__global__ __launch_bounds__(256) void k4_gates(const int* __restrict__ tok, const void* emb,
        const void* Uz_w, const void* Uz_b, const void* Wz_w, const void* Wz_b,
        const void* Ur_w, const void* Ur_b, const void* Wr_w, const void* Wr_b,
        const void* Uh_w, const void* Uh_b, const void* hidden,
        const int* flag, float* __restrict__ G) {
    int t = threadIdx.x, lane = t & 63, wv = t >> 6;
    int bf = flag[0];
    int wg = blockIdx.x * 4 + wv;       // 0..767
    int g = wg >> 8, i = wg & 255;
    const void* U = (g == 0 ? Uz_w : (g == 1 ? Ur_w : Uh_w));
    long urow = (long)i * VD;
    long yrow = (long)tok[0] * VD;
    float acc = 0.f;
    for (int c = 0; c < VD; c += 512) {
        long k = c + lane * 8;
        float4 u0 = ldf4(U, urow + k, bf),   u1 = ldf4(U, urow + k + 4, bf);
        float4 y0 = ldf4(emb, yrow + k, bf), y1 = ldf4(emb, yrow + k + 4, bf);
        acc = dot4(u0, y0, acc);
        acc = dot4(u1, y1, acc);
    }
    if (g < 2) {
        const void* W = (g == 0 ? Wz_w : Wr_w);
        long k = (long)lane * 4;
        acc = dot4(ldf4(W, (long)i * HD + k, bf), ldf4(hidden, k, bf), acc);
    }
    #pragma unroll
    for (int o = 32; o; o >>= 1) acc += __shfl_xor(acc, o);
    if (lane == 0) {
        float b;
        if (g == 0)      b = ldf(Uz_b, i, bf) + ldf(Wz_b, i, bf);
        else if (g == 1) b = ldf(Ur_b, i, bf) + ldf(Wr_b, i, bf);
        else             b = ldf(Uh_b, i, bf);
        G[wg] = acc + b;
    }
}

// K5: gates -> hidden_new; writes hn_f (f32 ws) and out[8192..8447]
__global__ __launch_bounds__(256) void k5_combine(const float* __restrict__ G,
        const float* __restrict__ Ci,
        const void* Cz_w, const void* Cz_b, const void* Cr_w, const void* Cr_b,
        const void* Wh_w, const void* Wh_b, const void* Ch_w, const void* Ch_b,
        const void* hidden, const int* flag,
        float* __restrict__ hn_f, void* out) {
    __shared__ __align__(16) float Cis[H2];
    __shared__ __align__(16) float rh[HD];
    int t = threadIdx.x; int bf = flag[0];
    Cis[t] = Ci[t]; Cis[t + 256] = Ci[t + 256];
    __syncthreads();
    float h = ldf(hidden, t, bf);
    float az = G[t] + ldf(Cz_b, t, bf);
    float ar = G[256 + t] + ldf(Cr_b, t, bf);
    for (int k = 0; k < H2; k += 4) {
        float4 c4 = *(const float4*)&Cis[k];
        az = dot4(ldf4(Cz_w, (long)t * H2 + k, bf), c4, az);
        ar = dot4(ldf4(Cr_w, (long)t * H2 + k, bf), c4, ar);
    }
    float z = 1.f / (1.f + __expf(-az));
    float r = 1.f / (1.f + __expf(-ar));
    rh[t] = r * h;
    __syncthreads();
    float ac = G[512 + t] + ldf(Wh_b, t, bf) + ldf(Ch_b, t, bf);
    for (int k = 0; k < HD; k += 4)
        ac = dot4(ldf4(Wh_w, (long)t * HD + k, bf), *(const float4*)&rh[k], ac);
    for (int k = 0; k < H2; k += 4)
        ac = dot4(ldf4(Ch_w, (long)t * H2 + k, bf), *(const float4*)&Cis[k], ac);
    float cc = tanhf(ac);
    float hnv = (1.f - z) * cc + z * h;
    hn_f[t] = hnv;
    stf(out, 8192 + t, bf, hnv);
}

// K6: raw logits -> out[0..8191]
__global__ __launch_bounds__(256) void k6_logits(const void* Vw, const void* Vb,
                                                 const float* __restrict__ hn,
                                                 const int* flag, void* out) {
    __shared__ __align__(16) float hs[HD];
    int t = threadIdx.x; int bf = flag[0];
    hs[t] = hn[t];
    __syncthreads();
    long j = (long)blockIdx.x * 256 + t;
    float acc = 0.f;
    for (int k = 0; k < HD; k += 4)
        acc = dot4(ldf4(Vw, j * HD + k, bf), *(const float4*)&hs[k], acc);
    stf(out, j, bf, acc + ldf(Vb, j, bf));
}

// K7: in-place log_softmax over out[0..8191]
__global__ __launch_bounds__(256) void k7_lsm(void* out, const int* flag) {
    __shared__ float sh[4];
    int t = threadIdx.x, lane = t & 63, wv = t >> 6;
    int bf = flag[0];
    float m = -1e30f;
    for (int i = t; i < VD; i += 256) m = fmaxf(m, ldf(out, i, bf));
    #pragma unroll
    for (int o = 32; o; o >>= 1) m = fmaxf(m, __shfl_xor(m, o));
    if (lane == 0) sh[wv] = m;
    __syncthreads();
    m = fmaxf(fmaxf(sh[0], sh[1]), fmaxf(sh[2], sh[3]));
    __syncthreads();
    float s = 0.f;
    for (int i = t; i < VD; i += 256) s += __expf(ldf(out, i, bf) - m);
    #pragma unroll
    for (int o = 32; o; o >>= 1) s += __shfl_xor(s, o);
    if (lane == 0) sh[wv] = s;
    __syncthreads();
    s = sh[0] + sh[1] + sh[2] + sh[3];
    float lse = m + __logf(s);
    for (int i = t; i < VD; i += 256)
        stf(out, i, bf, ldf(out, i, bf) - lse);
}

extern "C" void kernel_launch(void* const* d_in, const int* in_sizes, int n_in,
                              void* d_out, int out_size, void* d_ws, size_t ws_size,
                              hipStream_t stream) {
    const int*  tok    = (const int*)d_in[0];
    const void* hidden = d_in[1];
    const void* enc    = d_in[2];
    const void* emb    = d_in[3];
    const void* Uz_w = d_in[4],  *Uz_b = d_in[5];
    const void* Wz_w = d_in[6],  *Wz_b = d_in[7];
    const void* Cz_w = d_in[8],  *Cz_b = d_in[9];
    const void* Ur_w = d_in[10], *Ur_b = d_in[11];
    const void* Wr_w = d_in[12], *Wr_b = d_in[13];
    const void* Cr_w = d_in[14], *Cr_b = d_in[15];
    const void* Uh_w = d_in[16], *Uh_b = d_in[17];
    const void* Wh_w = d_in[18], *Wh_b = d_in[19];
    const void* Ch_w = d_in[20], *Ch_b = d_in[21];
    const void* Ua_w = d_in[22], *Ua_b = d_in[23];
    const void* Wa_w = d_in[24], *Wa_b = d_in[25];
    const void* Va_w = d_in[26], *Va_b = d_in[27];
    const void* V_w  = d_in[28], *V_b  = d_in[29];

    float* ws     = (float*)d_ws;
    int*   flag   = (int*)(ws + WS_FLAG);
    float* wa_h   = ws + WS_WAH;
    float* stats  = ws + WS_STATS;
    float* Ci     = ws + WS_CI;
    float* G      = ws + WS_G;
    float* hn_f   = ws + WS_HN;
    float* Eij    = ws + WS_EIJ;

    ks_sniff<<<1, 64, 0, stream>>>(emb, flag);
    k0_wah<<<1, 256, 0, stream>>>(Wa_w, Wa_b, hidden, flag, wa_h);
    k4_gates<<<192, 256, 0, stream>>>(tok, emb, Uz_w, Uz_b, Wz_w, Wz_b,
                                      Ur_w, Ur_b, Wr_w, Wr_b, Uh_w, Uh_b,
                                      hidden, flag, G);
    k1_scores<<<256, 256, 0, stream>>>(enc, Ua_w, Ua_b, Va_w, Va_b, wa_h, flag, Eij);
    k2_stats<<<1, 256, 0, stream>>>(Eij, stats, Ci);
    k3_ci<<<64, 256, 0, stream>>>(Eij, stats, enc, flag, d_out, Ci);
    k5_combine<<<1, 256, 0, stream>>>(G, Ci, Cz_w, Cz_b, Cr_w, Cr_b,
                                      Wh_w, Wh_b, Ch_w, Ch_b, hidden, flag,
                                      hn_f, d_out);
    k6_logits<<<32, 256, 0, stream>>>(V_w, V_b, hn_f, flag, d_out);
    k7_lsm<<<1, 256, 0, stream>>>(d_out, flag);
}

// Round 4
// 493.545 us; speedup vs baseline: 1.2313x; 1.2313x over previous
//
#include <hip/hip_runtime.h>
#include <hip/hip_bf16.h>

typedef unsigned int u32;

#define HD 256
#define VD 8192
#define SD 4096
#define H2 512

// ws float offsets
#define WS_WAH   0      // 256
#define WS_STATS 320    // 2
#define WS_CI    384    // 512
#define WS_G     896    // 768
#define WS_AZR   1664   // 768 (az, ar, pc)
#define WS_HN    2432   // 256
#define WS_EIJ   2688   // 4096

__device__ __forceinline__ float dot4(float4 a, float4 b, float acc) {
    acc = fmaf(a.x, b.x, acc); acc = fmaf(a.y, b.y, acc);
    acc = fmaf(a.z, b.z, acc); return fmaf(a.w, b.w, acc);
}
__device__ __forceinline__ float wred64(float v) {
    #pragma unroll
    for (int o = 32; o; o >>= 1) v += __shfl_xor(v, o);
    return v;
}

// KA: blocks 0..191 -> gate U/W matvecs (wave-per-row); block 192 -> wa_h
__global__ __launch_bounds__(256) void ka_gates(const int* __restrict__ tok,
        const float* __restrict__ emb,
        const float* __restrict__ Uz_w, const float* __restrict__ Uz_b,
        const float* __restrict__ Wz_w, const float* __restrict__ Wz_b,
        const float* __restrict__ Ur_w, const float* __restrict__ Ur_b,
        const float* __restrict__ Wr_w, const float* __restrict__ Wr_b,
        const float* __restrict__ Uh_w, const float* __restrict__ Uh_b,
        const float* __restrict__ Wa_w, const float* __restrict__ Wa_b,
        const float* __restrict__ hidden,
        float* __restrict__ G, float* __restrict__ wa_h) {
    int t = threadIdx.x, lane = t & 63, wv = t >> 6;
    if (blockIdx.x == 192) {
        // wa_h = Wa_w @ hidden + Wa_b  (thread-per-row)
        __shared__ __align__(16) float hs[HD];
        hs[t] = hidden[t];
        __syncthreads();
        float acc = 0.f;
        const float4* row = (const float4*)(Wa_w + (size_t)t * HD);
        #pragma unroll 4
        for (int k = 0; k < HD / 4; ++k)
            acc = dot4(row[k], *(const float4*)&hs[k * 4], acc);
        wa_h[t] = acc + Wa_b[t];
        return;
    }
    int wg = blockIdx.x * 4 + wv;       // 0..767
    int g = wg >> 8, i = wg & 255;
    const float* U = (g == 0 ? Uz_w : (g == 1 ? Ur_w : Uh_w)) + (size_t)i * VD;
    const float* y = emb + (size_t)tok[0] * VD;
    float acc = 0.f;
    for (int c = 0; c < VD; c += 512) {
        int k = c + lane * 8;
        acc = dot4(*(const float4*)(U + k),     *(const float4*)(y + k),     acc);
        acc = dot4(*(const float4*)(U + k + 4), *(const float4*)(y + k + 4), acc);
    }
    if (g < 2) {
        const float* W = (g == 0 ? Wz_w : Wr_w) + (size_t)i * HD;
        int k = lane * 4;
        acc = dot4(*(const float4*)(W + k), *(const float4*)(hidden + k), acc);
    }
    acc = wred64(acc);
    if (lane == 0) {
        float b;
        if (g == 0)      b = Uz_b[i] + Wz_b[i];
        else if (g == 1) b = Ur_b[i] + Wr_b[i];
        else             b = Uh_b[i];
        G[wg] = acc + b;
    }
}

// K1: Eij[s] = Va . tanh(wa_h + Ua_b + Ua_w @ enc[s]); 16 s-rows per block.
__global__ __launch_bounds__(256) void k1_scores(const float* __restrict__ enc,
        const float* __restrict__ Ua_w, const float* __restrict__ Ua_b,
        const float* __restrict__ Va_w, const float* __restrict__ Va_b,
        const float* __restrict__ wa_h, float* __restrict__ Eij) {
    __shared__ __align__(16) float encs[16 * H2];   // 32 KB
    int t = threadIdx.x;
    int lane = t & 63, sg = t >> 6;
    int h0 = lane * 4;
    long s0 = (long)blockIdx.x * 16;

    for (int i = t * 4; i < 16 * H2; i += 1024)
        *(float4*)&encs[i] = *(const float4*)(enc + s0 * H2 + i);
    __syncthreads();

    float acc[4][4];
    #pragma unroll
    for (int a = 0; a < 4; ++a)
        #pragma unroll
        for (int b = 0; b < 4; ++b) acc[a][b] = 0.f;

    const float* r0 = Ua_w + (size_t)(h0 + 0) * H2;
    const float* r1 = Ua_w + (size_t)(h0 + 1) * H2;
    const float* r2 = Ua_w + (size_t)(h0 + 2) * H2;
    const float* r3 = Ua_w + (size_t)(h0 + 3) * H2;
    for (int kc = 0; kc < H2; kc += 4) {
        float4 a0 = *(const float4*)(r0 + kc);
        float4 a1 = *(const float4*)(r1 + kc);
        float4 a2 = *(const float4*)(r2 + kc);
        float4 a3 = *(const float4*)(r3 + kc);
        #pragma unroll
        for (int ss = 0; ss < 4; ++ss) {
            float4 ev = *(const float4*)&encs[(sg * 4 + ss) * H2 + kc];
            acc[ss][0] = dot4(a0, ev, acc[ss][0]);
            acc[ss][1] = dot4(a1, ev, acc[ss][1]);
            acc[ss][2] = dot4(a2, ev, acc[ss][2]);
            acc[ss][3] = dot4(a3, ev, acc[ss][3]);
        }
    }

    float bias[4], va[4];
    #pragma unroll
    for (int j = 0; j < 4; ++j) {
        bias[j] = wa_h[h0 + j] + Ua_b[h0 + j];
        va[j]   = Va_w[h0 + j];
    }
    float vb = Va_b[0];
    #pragma unroll
    for (int ss = 0; ss < 4; ++ss) {
        float v = 0.f;
        #pragma unroll
        for (int j = 0; j < 4; ++j)
            v += va[j] * tanhf(acc[ss][j] + bias[j]);
        v = wred64(v);
        if (lane == 0) Eij[s0 + sg * 4 + ss] = v + vb;
    }
}

// K2: softmax stats over Eij + zero Ci
__global__ __launch_bounds__(256) void k2_stats(const float* __restrict__ Eij,
                                                float* __restrict__ stats,
                                                float* __restrict__ Ci) {
    __shared__ float sh[4];
    int t = threadIdx.x, lane = t & 63, wv = t >> 6;
    float m = -1e30f;
    for (int i = t; i < SD; i += 256) m = fmaxf(m, Eij[i]);
    #pragma unroll
    for (int o = 32; o; o >>= 1) m = fmaxf(m, __shfl_xor(m, o));
    if (lane == 0) sh[wv] = m;
    __syncthreads();
    m = fmaxf(fmaxf(sh[0], sh[1]), fmaxf(sh[2], sh[3]));
    __syncthreads();
    float s = 0.f;
    for (int i = t; i < SD; i += 256) s += __expf(Eij[i] - m);
    s = wred64(s);
    if (lane == 0) sh[wv] = s;
    __syncthreads();
    s = sh[0] + sh[1] + sh[2] + sh[3];
    if (t == 0) { stats[0] = m; stats[1] = 1.f / s; }
    for (int i = t; i < H2; i += 256) Ci[i] = 0.f;
}

// K3: aij -> out[8448..], Ci += sum aij*enc
__global__ __launch_bounds__(256) void k3_ci(const float* __restrict__ Eij,
                                             const float* __restrict__ stats,
                                             const float* __restrict__ enc,
                                             float* __restrict__ out,
                                             float* __restrict__ Ci) {
    __shared__ float a[64];
    int t = threadIdx.x;
    long s0 = (long)blockIdx.x * 64;
    if (t < 64) {
        float v = __expf(Eij[s0 + t] - stats[0]) * stats[1];
        a[t] = v;
        out[8448 + s0 + t] = v;
    }
    __syncthreads();
    float acc0 = 0.f, acc1 = 0.f;
    for (int s = 0; s < 64; ++s) {
        float av = a[s];
        const float* r = enc + (s0 + s) * H2;
        acc0 = fmaf(av, r[t], acc0);
        acc1 = fmaf(av, r[t + 256], acc1);
    }
    atomicAdd(Ci + t, acc0);
    atomicAdd(Ci + t + 256, acc1);
}

// K5a: AZR[wg] = G[wg] + C_g[i,:].Ci + gate bias   (wave-per-(gate,row))
__global__ __launch_bounds__(256) void k5a_cdots(const float* __restrict__ G,
        const float* __restrict__ Ci,
        const float* __restrict__ Cz_w, const float* __restrict__ Cz_b,
        const float* __restrict__ Cr_w, const float* __restrict__ Cr_b,
        const float* __restrict__ Ch_w, const float* __restrict__ Ch_b,
        const float* __restrict__ Wh_b,
        float* __restrict__ AZR) {
    int t = threadIdx.x, lane = t & 63, wv = t >> 6;
    int wg = blockIdx.x * 4 + wv;       // 0..767
    int g = wg >> 8, i = wg & 255;
    const float* C = (g == 0 ? Cz_w : (g == 1 ? Cr_w : Ch_w)) + (size_t)i * H2;
    int k = lane * 8;
    float acc = dot4(*(const float4*)(C + k),     *(const float4*)(Ci + k),     0.f);
    acc = dot4(*(const float4*)(C + k + 4), *(const float4*)(Ci + k + 4), acc);
    acc = wred64(acc);
    if (lane == 0) {
        float b;
        if (g == 0)      b = Cz_b[i];
        else if (g == 1) b = Cr_b[i];
        else             b = Wh_b[i] + Ch_b[i];
        AZR[wg] = G[wg] + acc + b;
    }
}

// K5c: hn[i] = (1-z_i)*tanh(pc_i + Wh[i,:].(sigmoid(ar)*h)) + z_i*h_i
// wave-per-row; sigmoid(ar[k]) recomputed per lane (4 each)
__global__ __launch_bounds__(256) void k5c_hnew(const float* __restrict__ AZR,
        const float* __restrict__ Wh_w, const float* __restrict__ hidden,
        float* __restrict__ hn_f, float* __restrict__ out) {
    int t = threadIdx.x, lane = t & 63, wv = t >> 6;
    int i = blockIdx.x * 4 + wv;        // 0..255
    int k = lane * 4;
    float4 ar4 = *(const float4*)(AZR + 256 + k);
    float4 h4  = *(const float4*)(hidden + k);
    float4 rh;
    rh.x = h4.x / (1.f + __expf(-ar4.x));
    rh.y = h4.y / (1.f + __expf(-ar4.y));
    rh.z = h4.z / (1.f + __expf(-ar4.z));
    rh.w = h4.w / (1.f + __expf(-ar4.w));
    float acc = dot4(*(const float4*)(Wh_w + (size_t)i * HD + k), rh, 0.f);
    acc = wred64(acc);
    if (lane == 0) {
        float c = tanhf(AZR[512 + i] + acc);
        float z = 1.f / (1.f + __expf(-AZR[i]));
        float hnv = (1.f - z) * c + z * hidden[i];
        hn_f[i] = hnv;
        out[8192 + i] = hnv;
    }
}

// K6: logits -> out[0..8191]  (wave-per-row, 16 rows/wave)
__global__ __launch_bounds__(256) void k6_logits(const float* __restrict__ Vw,
        const float* __restrict__ Vb, const float* __restrict__ hn,
        float* __restrict__ out) {
    int t = threadIdx.x, lane = t & 63, wv = t >> 6;
    float4 h4 = *(const float4*)(hn + lane * 4);
    long r0 = ((long)blockIdx.x * 4 + wv) * 16;
    for (int rr = 0; rr < 16; ++rr) {
        long j = r0 + rr;
        float acc = dot4(*(const float4*)(Vw + j * HD + lane * 4), h4, 0.f);
        acc = wred64(acc);
        if (lane == 0) out[j] = acc + Vb[j];
    }
}

// K7: in-place log_softmax over out[0..8191]
__global__ __launch_bounds__(256) void k7_lsm(float* __restrict__ out) {
    __shared__ float sh[4];
    int t = threadIdx.x, lane = t & 63, wv = t >> 6;
    float m = -1e30f;
    for (int i = t; i < VD; i += 256) m = fmaxf(m, out[i]);
    #pragma unroll
    for (int o = 32; o; o >>= 1) m = fmaxf(m, __shfl_xor(m, o));
    if (lane == 0) sh[wv] = m;
    __syncthreads();
    m = fmaxf(fmaxf(sh[0], sh[1]), fmaxf(sh[2], sh[3]));
    __syncthreads();
    float s = 0.f;
    for (int i = t; i < VD; i += 256) s += __expf(out[i] - m);
    s = wred64(s);
    if (lane == 0) sh[wv] = s;
    __syncthreads();
    s = sh[0] + sh[1] + sh[2] + sh[3];
    float lse = m + __logf(s);
    for (int i = t; i < VD; i += 256) out[i] = out[i] - lse;
}

extern "C" void kernel_launch(void* const* d_in, const int* in_sizes, int n_in,
                              void* d_out, int out_size, void* d_ws, size_t ws_size,
                              hipStream_t stream) {
    const int*   tok    = (const int*)d_in[0];
    const float* hidden = (const float*)d_in[1];
    const float* enc    = (const float*)d_in[2];
    const float* emb    = (const float*)d_in[3];
    const float* Uz_w = (const float*)d_in[4],  *Uz_b = (const float*)d_in[5];
    const float* Wz_w = (const float*)d_in[6],  *Wz_b = (const float*)d_in[7];
    const float* Cz_w = (const float*)d_in[8],  *Cz_b = (const float*)d_in[9];
    const float* Ur_w = (const float*)d_in[10], *Ur_b = (const float*)d_in[11];
    const float* Wr_w = (const float*)d_in[12], *Wr_b = (const float*)d_in[13];
    const float* Cr_w = (const float*)d_in[14], *Cr_b = (const float*)d_in[15];
    const float* Uh_w = (const float*)d_in[16], *Uh_b = (const float*)d_in[17];
    const float* Wh_w = (const float*)d_in[18], *Wh_b = (const float*)d_in[19];
    const float* Ch_w = (const float*)d_in[20], *Ch_b = (const float*)d_in[21];
    const float* Ua_w = (const float*)d_in[22], *Ua_b = (const float*)d_in[23];
    const float* Wa_w = (const float*)d_in[24], *Wa_b = (const float*)d_in[25];
    const float* Va_w = (const float*)d_in[26], *Va_b = (const float*)d_in[27];
    const float* V_w  = (const float*)d_in[28], *V_b  = (const float*)d_in[29];

    float* ws    = (float*)d_ws;
    float* wa_h  = ws + WS_WAH;
    float* stats = ws + WS_STATS;
    float* Ci    = ws + WS_CI;
    float* G     = ws + WS_G;
    float* AZR   = ws + WS_AZR;
    float* hn_f  = ws + WS_HN;
    float* Eij   = ws + WS_EIJ;
    float* out   = (float*)d_out;

    ka_gates<<<193, 256, 0, stream>>>(tok, emb, Uz_w, Uz_b, Wz_w, Wz_b,
                                      Ur_w, Ur_b, Wr_w, Wr_b, Uh_w, Uh_b,
                                      Wa_w, Wa_b, hidden, G, wa_h);
    k1_scores<<<256, 256, 0, stream>>>(enc, Ua_w, Ua_b, Va_w, Va_b, wa_h, Eij);
    k2_stats<<<1, 256, 0, stream>>>(Eij, stats, Ci);
    k3_ci<<<64, 256, 0, stream>>>(Eij, stats, enc, out, Ci);
    k5a_cdots<<<192, 256, 0, stream>>>(G, Ci, Cz_w, Cz_b, Cr_w, Cr_b,
                                       Ch_w, Ch_b, Wh_b, AZR);
    k5c_hnew<<<64, 256, 0, stream>>>(AZR, Wh_w, hidden, hn_f, out);
    k6_logits<<<128, 256, 0, stream>>>(V_w, V_b, hn_f, out);
    k7_lsm<<<1, 256, 0, stream>>>(out);
}